// Round 7
// baseline (272.478 us; speedup 1.0000x reference)
//
#include <hip/hip_runtime.h>
#include <cstdint>

#define B_  8
#define S_  2048
#define E_  1024
#define H_  128
#define NC_ 16          // chunks per sequence (S_/128)

typedef __attribute__((ext_vector_type(8))) short bf16x8;
typedef __attribute__((ext_vector_type(4))) float f32x4;

__device__ __forceinline__ short f2bf(float f){
  uint32_t u = __builtin_bit_cast(uint32_t, f);
  u = (u + 0x7fffu + ((u >> 16) & 1u)) >> 16;   // RNE
  return (short)u;
}
__device__ __forceinline__ float bf2f(short s){
  uint32_t u = ((uint32_t)(uint16_t)s) << 16;
  return __builtin_bit_cast(float, u);
}

// ---------------------------------------------------------------------------
// Kernel 1 v2: W (E,H) f32 -> Wfrag bf16 in MFMA-FRAGMENT ORDER.
// Wfrag[kc][s][tn][lane] (8 shorts each): lane=lr+16*lq holds
// W[kc*128+s*32+lq*8 .. +8][tn*16+lr] — exactly the per-lane B fragment
// proj's 16x16x32 MFMA needs. A wave's fragment load becomes 64x16B
// CONTIGUOUS (1KB, fully-used lines), enabling barrier-free proj.
// Each 32x32 tile block covers exactly one (kc,s) and two tn halves.
// ---------------------------------------------------------------------------
__global__ __launch_bounds__(256) void wt_kernel(
    const float* __restrict__ WQ, const float* __restrict__ WK,
    const float* __restrict__ WV,
    short* __restrict__ WfQ, short* __restrict__ WfK, short* __restrict__ WfV)
{
  int which = blockIdx.z;
  const float* W = which == 0 ? WQ : which == 1 ? WK : WV;
  short* Wf      = which == 0 ? WfQ : which == 1 ? WfK : WfV;
  int k0 = blockIdx.x * 32, n0 = blockIdx.y * 32;
  __shared__ float t[32][33];
  int tx = threadIdx.x & 31, ty = threadIdx.x >> 5;
  #pragma unroll
  for (int i = 0; i < 4; i++)
    t[ty + i * 8][tx] = W[(size_t)(k0 + ty + i * 8) * H_ + n0 + tx];
  __syncthreads();
  int tid = threadIdx.x;
  if (tid < 128){
    int tnh = tid >> 6;                  // 0..1 (which 16-col half)
    int lane = tid & 63;
    int lr = lane & 15, lq = lane >> 4;
    int tn = (n0 >> 4) + tnh;            // global tn 0..7
    int kc = k0 >> 7, s = (k0 >> 5) & 3;
    bf16x8 o;
    #pragma unroll
    for (int j = 0; j < 8; j++) o[j] = f2bf(t[lq * 8 + j][tnh * 16 + lr]);
    *(bf16x8*)(Wf + ((size_t)(((kc * 4 + s) * 8 + tn) * 64) + lane) * 8) = o;
  }
}

// ---------------------------------------------------------------------------
// Kernel 2 v7: projections, BARRIER-FREE via fragment-ordered Wfrag.
// Diagnosis r6: all LDS-staged variants sit at ~85-95 µs with NOTHING
// saturated (Mfma 5%, VALU 7%, HBM 17%, Occ 30%) — the per-chunk barrier
// lock-steps all waves onto one latency chain. Fix: B fragments read
// directly from Wfrag — 64 lanes x 16B contiguous per load (r2's failure
// was strided quarter-used lines; this is the corrected form). No LDS,
// no __syncthreads: 12 independent waves/CU free-run. B L2 traffic
// 786 MB ~= 23 µs, overlapped with A's HBM stream. MFMA operand values
// are bit-identical to r0 (same fragments, new addresses).
// ---------------------------------------------------------------------------
__global__ __launch_bounds__(256) void proj_kernel(
    const float* __restrict__ Xq, const float* __restrict__ Xk,
    const float* __restrict__ Xv,
    const short* __restrict__ Wfq, const short* __restrict__ Wfk,
    const short* __restrict__ Wfv,
    short* __restrict__ q, short* __restrict__ k,
    short* __restrict__ kT, short* __restrict__ vT)
{
  int which = blockIdx.y;
  const float* X  = which == 0 ? Xq  : which == 1 ? Xk  : Xv;
  const short* Wf = which == 0 ? Wfq : which == 1 ? Wfk : Wfv;

  int tid = threadIdx.x, lane = tid & 63, wave = tid >> 6;
  int lr = lane & 15, lq = lane >> 4;
  int rowbase = blockIdx.x * 64 + wave * 16;   // wave's 16 rows

  const float* xr = X + (size_t)(rowbase + lr) * E_ + lq * 8;
  const short* wl = Wf + (size_t)lane * 8;     // per-lane fragment base

  f32x4 acc[8];
  #pragma unroll
  for (int tn = 0; tn < 8; tn++) acc[tn] = (f32x4){0.f, 0.f, 0.f, 0.f};

  for (int kc = 0; kc < 8; kc++){              // 128-k chunks, no barriers
    // A for the whole chunk: 8 x f32x4 in flight (r0 pattern)
    f32x4 ar[8];
    #pragma unroll
    for (int s = 0; s < 4; s++){
      ar[2 * s]     = *(const f32x4*)(xr + kc * 128 + s * 32);
      ar[2 * s + 1] = *(const f32x4*)(xr + kc * 128 + s * 32 + 4);
    }
    #pragma unroll
    for (int s = 0; s < 4; s++){
      bf16x8 a;
      #pragma unroll
      for (int j = 0; j < 4; j++){
        a[j] = f2bf(ar[2 * s][j]); a[4 + j] = f2bf(ar[2 * s + 1][j]);
      }
      #pragma unroll
      for (int tn = 0; tn < 8; tn++){
        bf16x8 bfr = *(const bf16x8*)(
            wl + (size_t)(((kc * 4 + s) * 8 + tn) * 64) * 8);   // 1KB coalesced, L2
        acc[tn] = __builtin_amdgcn_mfma_f32_16x16x32_bf16(a, bfr, acc[tn], 0, 0, 0);
      }
    }
  }

  // ---- epilogue: C/D layout col=lane&15, row=(lane>>4)*4+reg ----
  if (which <= 1){
    short* P = which == 0 ? q : k;
    #pragma unroll
    for (int tn = 0; tn < 8; tn++)
      #pragma unroll
      for (int r4 = 0; r4 < 4; r4++)
        P[(size_t)(rowbase + lq * 4 + r4) * H_ + tn * 16 + lr] = f2bf(acc[tn][r4]);
  }
  if (which >= 1){
    short* T = which == 1 ? kT : vT;
    int b = rowbase >> 11, srow = rowbase & 2047;
    #pragma unroll
    for (int tn = 0; tn < 8; tn++){
      union { short sh[4]; uint2 u; } pk;
      #pragma unroll
      for (int r4 = 0; r4 < 4; r4++) pk.sh[r4] = f2bf(acc[tn][r4]);
      *(uint2*)(T + ((size_t)b * H_ + tn * 16 + lr) * S_ + srow + lq * 4) = pk.u;
    }
  }
}

// ---------------------------------------------------------------------------
// Kernel 3: per-chunk state M_j[h'][h] = sum_t V[t][h'] K[t][h].
// Col QUARTERS (32 h each); grid (15,4,B) — j=15 unused by exclusive prefix.
// ---------------------------------------------------------------------------
__global__ __launch_bounds__(256) void chunk_state(
    const short* __restrict__ vT, const short* __restrict__ kT,
    float* __restrict__ M)
{
  int j = blockIdx.x, qtr = blockIdx.y, b = blockIdx.z;
  int tid = threadIdx.x, lane = tid & 63, wave = tid >> 6;
  int wrow = wave * 32;
  int lr = lane & 15, lq = lane >> 4;

  __shared__ short As[128 * 136];   // vT rows (h' x t), 34.8 KB
  __shared__ short Bs[32 * 136];    // kT quarter rows (h x t), 8.7 KB

  const short* vtb = vT + (size_t)b * H_ * S_ + j * 128;
  const short* ktb = kT + (size_t)b * H_ * S_ + (size_t)qtr * 32 * S_ + j * 128;

  #pragma unroll
  for (int v = 0; v < 8; v++){
    int c = v * 256 + tid;
    int r = c >> 4, off = (c & 15) * 8;
    *(bf16x8*)(&As[r * 136 + off]) = *(const bf16x8*)(vtb + (size_t)r * S_ + off);
  }
  #pragma unroll
  for (int v = 0; v < 2; v++){
    int c = v * 256 + tid;
    int r = c >> 4, off = (c & 15) * 8;
    *(bf16x8*)(&Bs[r * 136 + off]) = *(const bf16x8*)(ktb + (size_t)r * S_ + off);
  }
  __syncthreads();

  f32x4 acc[2][2];
  #pragma unroll
  for (int a = 0; a < 2; a++)
    #pragma unroll
    for (int c = 0; c < 2; c++) acc[a][c] = (f32x4){0.f, 0.f, 0.f, 0.f};

  #pragma unroll
  for (int s = 0; s < 4; s++){
    int t0 = s * 32;
    bf16x8 af[2], bf[2];
    #pragma unroll
    for (int tm = 0; tm < 2; tm++)
      af[tm] = *(const bf16x8*)(&As[(wrow + tm * 16 + lr) * 136 + t0 + lq * 8]);
    #pragma unroll
    for (int tn = 0; tn < 2; tn++)
      bf[tn] = *(const bf16x8*)(&Bs[(tn * 16 + lr) * 136 + t0 + lq * 8]);
    #pragma unroll
    for (int tm = 0; tm < 2; tm++)
      #pragma unroll
      for (int tn = 0; tn < 2; tn++)
        acc[tm][tn] = __builtin_amdgcn_mfma_f32_16x16x32_bf16(
            af[tm], bf[tn], acc[tm][tn], 0, 0, 0);
  }

  float* mb = M + (size_t)(b * NC_ + j) * 16384;
  #pragma unroll
  for (int tm = 0; tm < 2; tm++)
    #pragma unroll
    for (int tn = 0; tn < 2; tn++)
      #pragma unroll
      for (int r4 = 0; r4 < 4; r4++){
        int row = wrow + tm * 16 + lq * 4 + r4;
        int col = qtr * 32 + tn * 16 + lr;
        mb[row * 128 + col] = acc[tm][tn][r4];
      }
}

// ---------------------------------------------------------------------------
// Kernel 4: exclusive prefix of M over chunks -> bf16 hi + residual lo.
// float2/thread, grid (32,B) = 256 blocks. Loads only M_0..M_14.
// ---------------------------------------------------------------------------
__global__ __launch_bounds__(256) void prefix_state(
    const float* __restrict__ M, short* __restrict__ Shi, short* __restrict__ Slo)
{
  int b = blockIdx.y;
  int idx = (blockIdx.x * 256 + threadIdx.x) * 2;
  float2 mv[NC_ - 1];
  #pragma unroll
  for (int j = 0; j < NC_ - 1; j++)
    mv[j] = *(const float2*)(M + (size_t)(b * NC_ + j) * 16384 + idx);

  float r0 = 0.f, r1 = 0.f;
  #pragma unroll
  for (int j = 0; j < NC_; j++){
    size_t o = (size_t)(b * NC_ + j) * 16384 + idx;
    short h0 = f2bf(r0), h1 = f2bf(r1);
    short l0 = f2bf(r0 - bf2f(h0)), l1 = f2bf(r1 - bf2f(h1));
    union { short s[2]; uint32_t u; } ph, pl;
    ph.s[0] = h0; ph.s[1] = h1;
    pl.s[0] = l0; pl.s[1] = l1;
    *(uint32_t*)(Shi + o) = ph.u;
    *(uint32_t*)(Slo + o) = pl.u;
    if (j < NC_ - 1){ r0 += mv[j].x; r1 += mv[j].y; }
  }
}

// ---------------------------------------------------------------------------
// Kernel 5: per (b, chunk i, row-QUARTER): 32 rows of
//   O = (Q_i K_i^T . tril) V_i + Q_i (State_hi + State_lo)
// r3 verbatim. All global tile loads issued at kernel entry (T14). 4 barriers.
// ---------------------------------------------------------------------------
__global__ __launch_bounds__(256) void passC(
    const short* __restrict__ qb, const short* __restrict__ kb,
    const short* __restrict__ vT, const short* __restrict__ Shi,
    const short* __restrict__ Slo, float* __restrict__ out)
{
  int i = blockIdx.x, qtr = blockIdx.y, b = blockIdx.z;
  int roff = qtr * 32;
  int tid = threadIdx.x, lane = tid & 63, wave = tid >> 6;
  int wcol = wave * 32;
  int lr = lane & 15, lq = lane >> 4;

  __shared__ short Ss[32 * 136];    // masked scores (8.7 KB)
  __shared__ short Bt0[128 * 136];  // K, then Shi  (34.8 KB)
  __shared__ short Bt1[128 * 136];  // V, then Slo  (34.8 KB)

  const short* qbase = qb + ((size_t)b * S_ + i * 128 + roff) * H_;
  const short* kbase = kb + ((size_t)b * S_ + i * 128) * H_;
  const short* vtb   = vT + (size_t)b * H_ * S_ + i * 128;
  const short* shib  = Shi + (size_t)(b * NC_ + i) * 16384;
  const short* slob  = Slo + (size_t)(b * NC_ + i) * 16384;

  // ---- issue ALL global loads up front: 40 x 16B per lane in flight ----
  bf16x8 kst[8], vst[8], hst[8], lst[8];
  #pragma unroll
  for (int v = 0; v < 8; v++){
    int c = v * 256 + tid;
    int r = c >> 4, off = (c & 15) * 8;
    kst[v] = *(const bf16x8*)(kbase + (size_t)r * H_ + off);
    vst[v] = *(const bf16x8*)(vtb  + (size_t)r * S_ + off);
    hst[v] = *(const bf16x8*)(shib + (size_t)r * 128 + off);
    lst[v] = *(const bf16x8*)(slob + (size_t)r * 128 + off);
  }
  bf16x8 aq[2][4];   // Q rows tm*16+lr (32 rows of this quarter)
  #pragma unroll
  for (int tm = 0; tm < 2; tm++)
    #pragma unroll
    for (int hs = 0; hs < 4; hs++)
      aq[tm][hs] = *(const bf16x8*)(
          qbase + (size_t)(tm * 16 + lr) * H_ + hs * 32 + lq * 8);

  // K -> Bt0
  #pragma unroll
  for (int v = 0; v < 8; v++){
    int c = v * 256 + tid;
    int r = c >> 4, off = (c & 15) * 8;
    *(bf16x8*)(&Bt0[r * 136 + off]) = kst[v];
  }
  __syncthreads();                           // barrier 1

  f32x4 accS[2][2];
  #pragma unroll
  for (int a = 0; a < 2; a++)
    #pragma unroll
    for (int c = 0; c < 2; c++) accS[a][c] = (f32x4){0.f, 0.f, 0.f, 0.f};

  // ---- phase 1: S = Q K^T, wave's t-slice = wcol..wcol+31 ----
  #pragma unroll
  for (int hs = 0; hs < 4; hs++){
    bf16x8 bf[2];
    #pragma unroll
    for (int tn = 0; tn < 2; tn++)
      bf[tn] = *(const bf16x8*)(&Bt0[(wcol + tn * 16 + lr) * 136 + hs * 32 + lq * 8]);
    #pragma unroll
    for (int tm = 0; tm < 2; tm++)
      #pragma unroll
      for (int tn = 0; tn < 2; tn++)
        accS[tm][tn] = __builtin_amdgcn_mfma_f32_16x16x32_bf16(
            aq[tm][hs], bf[tn], accS[tm][tn], 0, 0, 0);
  }

  // ---- phase 2: mask + bf16 -> Ss; land V -> Bt1 ----
  #pragma unroll
  for (int tm = 0; tm < 2; tm++)
    #pragma unroll
    for (int tn = 0; tn < 2; tn++)
      #pragma unroll
      for (int r4 = 0; r4 < 4; r4++){
        int row = tm * 16 + lq * 4 + r4;            // local row 0..31
        int col = wcol + tn * 16 + lr;              // t index 0..127
        float vv = (col <= roff + row) ? accS[tm][tn][r4] : 0.f;
        Ss[row * 136 + col] = f2bf(vv);
      }
  #pragma unroll
  for (int v = 0; v < 8; v++){
    int c = v * 256 + tid;
    int r = c >> 4, off = (c & 15) * 8;
    *(bf16x8*)(&Bt1[r * 136 + off]) = vst[v];
  }
  f32x4 acc[2][2];
  #pragma unroll
  for (int a = 0; a < 2; a++)
    #pragma unroll
    for (int c = 0; c < 2; c++) acc[a][c] = (f32x4){0.f, 0.f, 0.f, 0.f};
  __syncthreads();                           // barrier 2

  // ---- phase 3a: O += S V, wave's h'-slice = wcol; land Shi -> Bt0 ----
  #pragma unroll
  for (int s = 0; s < 4; s++){
    int t0 = s * 32;
    bf16x8 af[2], bf[2];
    #pragma unroll
    for (int tm = 0; tm < 2; tm++)
      af[tm] = *(const bf16x8*)(&Ss[(tm * 16 + lr) * 136 + t0 + lq * 8]);
    #pragma unroll
    for (int tn = 0; tn < 2; tn++)
      bf[tn] = *(const bf16x8*)(&Bt1[(wcol + tn * 16 + lr) * 136 + t0 + lq * 8]);
    #pragma unroll
    for (int tm = 0; tm < 2; tm++)
      #pragma unroll
      for (int tn = 0; tn < 2; tn++)
        acc[tm][tn] = __builtin_amdgcn_mfma_f32_16x16x32_bf16(
            af[tm], bf[tn], acc[tm][tn], 0, 0, 0);
  }
  #pragma unroll
  for (int v = 0; v < 8; v++){
    int c = v * 256 + tid;
    int r = c >> 4, off = (c & 15) * 8;
    *(bf16x8*)(&Bt0[r * 136 + off]) = hst[v];
  }
  __syncthreads();                           // barrier 3

  // ---- phase 3b-hi: O += Q * State_hi (Bt0); land Slo -> Bt1 ----
  #pragma unroll
  for (int hs = 0; hs < 4; hs++){
    bf16x8 bf[2];
    #pragma unroll
    for (int tn = 0; tn < 2; tn++)
      bf[tn] = *(const bf16x8*)(&Bt0[(wcol + tn * 16 + lr) * 136 + hs * 32 + lq * 8]);
    #pragma unroll
    for (int tm = 0; tm < 2; tm++)
      #pragma unroll
      for (int tn = 0; tn < 2; tn++)
        acc[tm][tn] = __builtin_amdgcn_mfma_f32_16x16x32_bf16(
            aq[tm][hs], bf[tn], acc[tm][tn], 0, 0, 0);
  }
  #pragma unroll
  for (int v = 0; v < 8; v++){
    int c = v * 256 + tid;
    int r = c >> 4, off = (c & 15) * 8;
    *(bf16x8*)(&Bt1[r * 136 + off]) = lst[v];
  }
  __syncthreads();                           // barrier 4

  // ---- phase 3b-lo: O += Q * State_lo (Bt1) ----
  #pragma unroll
  for (int hs = 0; hs < 4; hs++){
    bf16x8 bf[2];
    #pragma unroll
    for (int tn = 0; tn < 2; tn++)
      bf[tn] = *(const bf16x8*)(&Bt1[(wcol + tn * 16 + lr) * 136 + hs * 32 + lq * 8]);
    #pragma unroll
    for (int tm = 0; tm < 2; tm++)
      #pragma unroll
      for (int tn = 0; tn < 2; tn++)
        acc[tm][tn] = __builtin_amdgcn_mfma_f32_16x16x32_bf16(
            aq[tm][hs], bf[tn], acc[tm][tn], 0, 0, 0);
  }

  // ---- epilogue ----
  float* ob = out + ((size_t)b * S_ + i * 128 + roff) * H_;
  #pragma unroll
  for (int tm = 0; tm < 2; tm++)
    #pragma unroll
    for (int tn = 0; tn < 2; tn++)
      #pragma unroll
      for (int r4 = 0; r4 < 4; r4++){
        int row = tm * 16 + lq * 4 + r4;
        int col = wcol + tn * 16 + lr;
        ob[(size_t)row * H_ + col] = acc[tm][tn][r4];
      }
}

// ---------------------------------------------------------------------------
extern "C" void kernel_launch(void* const* d_in, const int* in_sizes, int n_in,
                              void* d_out, int out_size, void* d_ws, size_t ws_size,
                              hipStream_t stream) {
  // setup_inputs order: key, query, value, W_Q, W_K, W_V (all fp32)
  const float* key   = (const float*)d_in[0];
  const float* query = (const float*)d_in[1];
  const float* value = (const float*)d_in[2];
  const float* WQ    = (const float*)d_in[3];
  const float* WK    = (const float*)d_in[4];
  const float* WV    = (const float*)d_in[5];
  float* out = (float*)d_out;

  char* w = (char*)d_ws;
  short* WfQ = (short*)(w + 0);                       // 3 x 256 KB frag-order
  short* WfK = (short*)(w + 262144);
  short* WfV = (short*)(w + 524288);
  size_t o = 786432;
  short* q  = (short*)(w + o); o += 4194304;          // (B,S,H) bf16
  short* k  = (short*)(w + o); o += 4194304;
  short* kT = (short*)(w + o); o += 4194304;          // (B,H,S) bf16
  short* vT = (short*)(w + o); o += 4194304;
  float* M  = (float*)(w + o); o += 8388608;          // (B,NC,128,128) f32
  short* Shi= (short*)(w + o); o += 4194304;          // exclusive prefix, bf16 hi
  short* Slo= (short*)(w + o); o += 4194304;          // bf16 residual

  wt_kernel   <<<dim3(32, 4, 3),       256, 0, stream>>>(WQ, WK, WV, WfQ, WfK, WfV);
  proj_kernel <<<dim3(256, 3),         256, 0, stream>>>(query, key, value,
                                                         WfQ, WfK, WfV, q, k, kT, vT);
  chunk_state <<<dim3(15, 4, B_),      256, 0, stream>>>(vT, kT, M);
  prefix_state<<<dim3(32, B_),         256, 0, stream>>>(M, Shi, Slo);
  passC       <<<dim3(NC_, 4, B_),     256, 0, stream>>>(q, k, vT, Shi, Slo, out);
}

// Round 8
// 237.512 us; speedup vs baseline: 1.1472x; 1.1472x over previous
//
#include <hip/hip_runtime.h>
#include <cstdint>

#define B_  8
#define S_  2048
#define E_  1024
#define H_  128
#define NC_ 16          // chunks per sequence (S_/128)

typedef __attribute__((ext_vector_type(8))) short bf16x8;
typedef __attribute__((ext_vector_type(4))) float f32x4;

__device__ __forceinline__ short f2bf(float f){
  uint32_t u = __builtin_bit_cast(uint32_t, f);
  u = (u + 0x7fffu + ((u >> 16) & 1u)) >> 16;   // RNE
  return (short)u;
}
__device__ __forceinline__ float bf2f(short s){
  uint32_t u = ((uint32_t)(uint16_t)s) << 16;
  return __builtin_bit_cast(float, u);
}

// ---------------------------------------------------------------------------
// Kernel 1: W (E,H) f32 -> Wt (H,E) bf16, LDS-tiled transpose
// ---------------------------------------------------------------------------
__global__ __launch_bounds__(256) void wt_kernel(
    const float* __restrict__ WQ, const float* __restrict__ WK,
    const float* __restrict__ WV,
    short* __restrict__ WtQ, short* __restrict__ WtK, short* __restrict__ WtV)
{
  int which = blockIdx.z;
  const float* W = which == 0 ? WQ : which == 1 ? WK : WV;
  short* Wt      = which == 0 ? WtQ : which == 1 ? WtK : WtV;
  int k0 = blockIdx.x * 32, n0 = blockIdx.y * 32;
  __shared__ float t[32][33];
  int tx = threadIdx.x & 31, ty = threadIdx.x >> 5;
  #pragma unroll
  for (int i = 0; i < 4; i++)
    t[ty + i * 8][tx] = W[(size_t)(k0 + ty + i * 8) * H_ + n0 + tx];
  __syncthreads();
  #pragma unroll
  for (int i = 0; i < 4; i++)
    Wt[(size_t)(n0 + ty + i * 8) * E_ + k0 + tx] = f2bf(t[tx][ty + i * 8]);
}

// ---------------------------------------------------------------------------
// Kernel 2: projections — r0 VERBATIM (confirmed optimum, 82-88 µs).
// Closed ledger: r0=82-88, r1 dbuf=94, r3 A-via-LDS=96, r7 fragorder
// direct=125, r2 strided direct=145. Direct-from-global MFMA feeds lose
// to LDS staging regardless of coalescing; the per-chunk barrier is NOT
// the limiter. Do not touch.
// ---------------------------------------------------------------------------
__global__ __launch_bounds__(256) void proj_kernel(
    const float* __restrict__ Xq, const float* __restrict__ Xk,
    const float* __restrict__ Xv,
    const short* __restrict__ Wtq, const short* __restrict__ Wtk,
    const short* __restrict__ Wtv,
    short* __restrict__ q, short* __restrict__ k,
    short* __restrict__ kT, short* __restrict__ vT)
{
  int which = blockIdx.y;
  const float* X  = which == 0 ? Xq  : which == 1 ? Xk  : Xv;
  const short* Wt = which == 0 ? Wtq : which == 1 ? Wtk : Wtv;

  int tid = threadIdx.x, lane = tid & 63, wave = tid >> 6;
  int lr = lane & 15, lq = lane >> 4;
  int rowbase = blockIdx.x * 64 + wave * 16;   // wave's 16 rows

  __shared__ short Bs[128 * 136];              // padded stride 136 (34.8 KB)

  const float* xr = X + (size_t)(rowbase + lr) * E_ + lq * 8;

  f32x4 acc[8];
  #pragma unroll
  for (int tn = 0; tn < 8; tn++) acc[tn] = (f32x4){0.f, 0.f, 0.f, 0.f};

  for (int kc = 0; kc < 8; kc++){              // 128-k chunks
    if (kc) __syncthreads();                   // prev chunk's reads done
    // volley: stage B chunk, 128 rows x 128 shorts; 8 x 16B per thread
    #pragma unroll
    for (int v = 0; v < 8; v++){
      int c = v * 256 + tid;
      int n = c >> 4, off = (c & 15) * 8;
      *(bf16x8*)(&Bs[n * 136 + off]) =
          *(const bf16x8*)(Wt + (size_t)n * E_ + kc * 128 + off);
    }
    // A for the whole chunk: 8 x f32x4 in flight
    f32x4 ar[8];
    #pragma unroll
    for (int s = 0; s < 4; s++){
      ar[2 * s]     = *(const f32x4*)(xr + kc * 128 + s * 32);
      ar[2 * s + 1] = *(const f32x4*)(xr + kc * 128 + s * 32 + 4);
    }
    __syncthreads();                           // single drain per chunk
    #pragma unroll
    for (int s = 0; s < 4; s++){
      bf16x8 a;
      #pragma unroll
      for (int j = 0; j < 4; j++){
        a[j] = f2bf(ar[2 * s][j]); a[4 + j] = f2bf(ar[2 * s + 1][j]);
      }
      #pragma unroll
      for (int tn = 0; tn < 8; tn++){
        bf16x8 bfr = *(const bf16x8*)(&Bs[(tn * 16 + lr) * 136 + s * 32 + lq * 8]);
        acc[tn] = __builtin_amdgcn_mfma_f32_16x16x32_bf16(a, bfr, acc[tn], 0, 0, 0);
      }
    }
  }

  // ---- epilogue: C/D layout col=lane&15, row=(lane>>4)*4+reg ----
  if (which <= 1){
    short* P = which == 0 ? q : k;
    #pragma unroll
    for (int tn = 0; tn < 8; tn++)
      #pragma unroll
      for (int r4 = 0; r4 < 4; r4++)
        P[(size_t)(rowbase + lq * 4 + r4) * H_ + tn * 16 + lr] = f2bf(acc[tn][r4]);
  }
  if (which >= 1){
    short* T = which == 1 ? kT : vT;
    int b = rowbase >> 11, srow = rowbase & 2047;
    #pragma unroll
    for (int tn = 0; tn < 8; tn++){
      union { short sh[4]; uint2 u; } pk;
      #pragma unroll
      for (int r4 = 0; r4 < 4; r4++) pk.sh[r4] = f2bf(acc[tn][r4]);
      *(uint2*)(T + ((size_t)b * H_ + tn * 16 + lr) * S_ + srow + lq * 4) = pk.u;
    }
  }
}

// ---------------------------------------------------------------------------
// Kernel 3 (NEW): fused chunk_state + exclusive prefix.
// Grid (4 h'-slices, 2 h-halves, B) = 64 blocks. Block owns a 32x64 tile
// of the state matrix; the running prefix LIVES IN THE MFMA ACCUMULATOR:
// per chunk j, write acc (= sum_{j'<j} M_j') as Shi/Slo[j] (hi/lo bf16
// split), then acc += V_j^T K_j contribution via 4 MFMA t-steps.
// Eliminates the M array (8MB write + 15MB read), the prefix_state
// kernel, and one launch gap. Double-buffered LDS, ONE barrier per j
// (stage(j) overwrite of buf[j&1] is gated by barrier(j-1): every wave
// past it has finished compute(j-2), the last reader of that buffer).
// Unlike r4's failed fusion: no extra VGPR in passC, no serial j-loop on
// the O-critical path — the j-loop IS the MFMA accumulation here.
// ---------------------------------------------------------------------------
__global__ __launch_bounds__(256) void fused_state(
    const short* __restrict__ vT, const short* __restrict__ kT,
    short* __restrict__ Shi, short* __restrict__ Slo)
{
  int rh = blockIdx.x;            // h'-slice (32 rows of V-dim)
  int ch = blockIdx.y;            // h-half  (64 cols of K-dim)
  int b  = blockIdx.z;
  int tid = threadIdx.x, lane = tid & 63, wave = tid >> 6;
  int lr = lane & 15, lq = lane >> 4;

  __shared__ short As[2][32 * 136];   // vT slice rows (h' x t), 2x8.7 KB
  __shared__ short Bs[2][64 * 136];   // kT half rows (h x t),  2x17.4 KB

  const short* vtb = vT + (size_t)b * H_ * S_ + (size_t)(rh * 32) * S_;
  const short* ktb = kT + (size_t)b * H_ * S_ + (size_t)(ch * 64) * S_;

  f32x4 acc[2];
  acc[0] = (f32x4){0.f, 0.f, 0.f, 0.f};
  acc[1] = (f32x4){0.f, 0.f, 0.f, 0.f};

  for (int j = 0; j < NC_; j++){
    // ---- exclusive prefix for chunk j: acc -> Shi/Slo[j] ----
    size_t obase = (size_t)(b * NC_ + j) * 16384;
    #pragma unroll
    for (int tm = 0; tm < 2; tm++)
      #pragma unroll
      for (int r4 = 0; r4 < 4; r4++){
        int row = rh * 32 + tm * 16 + lq * 4 + r4;   // C/D: row=(lane>>4)*4+reg
        int col = ch * 64 + wave * 16 + lr;          //      col=lane&15
        float v = acc[tm][r4];
        short h = f2bf(v);
        Shi[obase + (size_t)row * 128 + col] = h;
        Slo[obase + (size_t)row * 128 + col] = f2bf(v - bf2f(h));
      }
    if (j == NC_ - 1) break;       // M_15 never needed

    // ---- stage chunk j tiles into buf = j&1 ----
    int buf = j & 1;
    #pragma unroll
    for (int v = 0; v < 2; v++){
      int c = v * 256 + tid;
      int r = c >> 4, off = (c & 15) * 8;
      *(bf16x8*)(&As[buf][r * 136 + off]) =
          *(const bf16x8*)(vtb + (size_t)r * S_ + j * 128 + off);
    }
    #pragma unroll
    for (int v = 0; v < 4; v++){
      int c = v * 256 + tid;
      int r = c >> 4, off = (c & 15) * 8;
      *(bf16x8*)(&Bs[buf][r * 136 + off]) =
          *(const bf16x8*)(ktb + (size_t)r * S_ + j * 128 + off);
    }
    __syncthreads();

    // ---- acc += M_j: 4 barrier-free t-steps ----
    #pragma unroll
    for (int s = 0; s < 4; s++){
      int t0 = s * 32;
      bf16x8 bfr = *(const bf16x8*)(&Bs[buf][(wave * 16 + lr) * 136 + t0 + lq * 8]);
      #pragma unroll
      for (int tm = 0; tm < 2; tm++){
        bf16x8 af = *(const bf16x8*)(&As[buf][(tm * 16 + lr) * 136 + t0 + lq * 8]);
        acc[tm] = __builtin_amdgcn_mfma_f32_16x16x32_bf16(af, bfr, acc[tm], 0, 0, 0);
      }
    }
  }
}

// ---------------------------------------------------------------------------
// Kernel 4: per (b, chunk i, row-QUARTER): 32 rows of
//   O = (Q_i K_i^T . tril) V_i + Q_i (State_hi + State_lo)
// r3 verbatim. All global tile loads issued at kernel entry (T14). 4 barriers.
// ---------------------------------------------------------------------------
__global__ __launch_bounds__(256) void passC(
    const short* __restrict__ qb, const short* __restrict__ kb,
    const short* __restrict__ vT, const short* __restrict__ Shi,
    const short* __restrict__ Slo, float* __restrict__ out)
{
  int i = blockIdx.x, qtr = blockIdx.y, b = blockIdx.z;
  int roff = qtr * 32;
  int tid = threadIdx.x, lane = tid & 63, wave = tid >> 6;
  int wcol = wave * 32;
  int lr = lane & 15, lq = lane >> 4;

  __shared__ short Ss[32 * 136];    // masked scores (8.7 KB)
  __shared__ short Bt0[128 * 136];  // K, then Shi  (34.8 KB)
  __shared__ short Bt1[128 * 136];  // V, then Slo  (34.8 KB)

  const short* qbase = qb + ((size_t)b * S_ + i * 128 + roff) * H_;
  const short* kbase = kb + ((size_t)b * S_ + i * 128) * H_;
  const short* vtb   = vT + (size_t)b * H_ * S_ + i * 128;
  const short* shib  = Shi + (size_t)(b * NC_ + i) * 16384;
  const short* slob  = Slo + (size_t)(b * NC_ + i) * 16384;

  // ---- issue ALL global loads up front: 40 x 16B per lane in flight ----
  bf16x8 kst[8], vst[8], hst[8], lst[8];
  #pragma unroll
  for (int v = 0; v < 8; v++){
    int c = v * 256 + tid;
    int r = c >> 4, off = (c & 15) * 8;
    kst[v] = *(const bf16x8*)(kbase + (size_t)r * H_ + off);
    vst[v] = *(const bf16x8*)(vtb  + (size_t)r * S_ + off);
    hst[v] = *(const bf16x8*)(shib + (size_t)r * 128 + off);
    lst[v] = *(const bf16x8*)(slob + (size_t)r * 128 + off);
  }
  bf16x8 aq[2][4];   // Q rows tm*16+lr (32 rows of this quarter)
  #pragma unroll
  for (int tm = 0; tm < 2; tm++)
    #pragma unroll
    for (int hs = 0; hs < 4; hs++)
      aq[tm][hs] = *(const bf16x8*)(
          qbase + (size_t)(tm * 16 + lr) * H_ + hs * 32 + lq * 8);

  // K -> Bt0
  #pragma unroll
  for (int v = 0; v < 8; v++){
    int c = v * 256 + tid;
    int r = c >> 4, off = (c & 15) * 8;
    *(bf16x8*)(&Bt0[r * 136 + off]) = kst[v];
  }
  __syncthreads();                           // barrier 1

  f32x4 accS[2][2];
  #pragma unroll
  for (int a = 0; a < 2; a++)
    #pragma unroll
    for (int c = 0; c < 2; c++) accS[a][c] = (f32x4){0.f, 0.f, 0.f, 0.f};

  // ---- phase 1: S = Q K^T, wave's t-slice = wcol..wcol+31 ----
  #pragma unroll
  for (int hs = 0; hs < 4; hs++){
    bf16x8 bf[2];
    #pragma unroll
    for (int tn = 0; tn < 2; tn++)
      bf[tn] = *(const bf16x8*)(&Bt0[(wcol + tn * 16 + lr) * 136 + hs * 32 + lq * 8]);
    #pragma unroll
    for (int tm = 0; tm < 2; tm++)
      #pragma unroll
      for (int tn = 0; tn < 2; tn++)
        accS[tm][tn] = __builtin_amdgcn_mfma_f32_16x16x32_bf16(
            aq[tm][hs], bf[tn], accS[tm][tn], 0, 0, 0);
  }

  // ---- phase 2: mask + bf16 -> Ss; land V -> Bt1 ----
  #pragma unroll
  for (int tm = 0; tm < 2; tm++)
    #pragma unroll
    for (int tn = 0; tn < 2; tn++)
      #pragma unroll
      for (int r4 = 0; r4 < 4; r4++){
        int row = tm * 16 + lq * 4 + r4;            // local row 0..31
        int col = wcol + tn * 16 + lr;              // t index 0..127
        float vv = (col <= roff + row) ? accS[tm][tn][r4] : 0.f;
        Ss[row * 136 + col] = f2bf(vv);
      }
  #pragma unroll
  for (int v = 0; v < 8; v++){
    int c = v * 256 + tid;
    int r = c >> 4, off = (c & 15) * 8;
    *(bf16x8*)(&Bt1[r * 136 + off]) = vst[v];
  }
  f32x4 acc[2][2];
  #pragma unroll
  for (int a = 0; a < 2; a++)
    #pragma unroll
    for (int c = 0; c < 2; c++) acc[a][c] = (f32x4){0.f, 0.f, 0.f, 0.f};
  __syncthreads();                           // barrier 2

  // ---- phase 3a: O += S V, wave's h'-slice = wcol; land Shi -> Bt0 ----
  #pragma unroll
  for (int s = 0; s < 4; s++){
    int t0 = s * 32;
    bf16x8 af[2], bf[2];
    #pragma unroll
    for (int tm = 0; tm < 2; tm++)
      af[tm] = *(const bf16x8*)(&Ss[(tm * 16 + lr) * 136 + t0 + lq * 8]);
    #pragma unroll
    for (int tn = 0; tn < 2; tn++)
      bf[tn] = *(const bf16x8*)(&Bt1[(wcol + tn * 16 + lr) * 136 + t0 + lq * 8]);
    #pragma unroll
    for (int tm = 0; tm < 2; tm++)
      #pragma unroll
      for (int tn = 0; tn < 2; tn++)
        acc[tm][tn] = __builtin_amdgcn_mfma_f32_16x16x32_bf16(
            af[tm], bf[tn], acc[tm][tn], 0, 0, 0);
  }
  #pragma unroll
  for (int v = 0; v < 8; v++){
    int c = v * 256 + tid;
    int r = c >> 4, off = (c & 15) * 8;
    *(bf16x8*)(&Bt0[r * 136 + off]) = hst[v];
  }
  __syncthreads();                           // barrier 3

  // ---- phase 3b-hi: O += Q * State_hi (Bt0); land Slo -> Bt1 ----
  #pragma unroll
  for (int hs = 0; hs < 4; hs++){
    bf16x8 bf[2];
    #pragma unroll
    for (int tn = 0; tn < 2; tn++)
      bf[tn] = *(const bf16x8*)(&Bt0[(wcol + tn * 16 + lr) * 136 + hs * 32 + lq * 8]);
    #pragma unroll
    for (int tm = 0; tm < 2; tm++)
      #pragma unroll
      for (int tn = 0; tn < 2; tn++)
        acc[tm][tn] = __builtin_amdgcn_mfma_f32_16x16x32_bf16(
            aq[tm][hs], bf[tn], acc[tm][tn], 0, 0, 0);
  }
  #pragma unroll
  for (int v = 0; v < 8; v++){
    int c = v * 256 + tid;
    int r = c >> 4, off = (c & 15) * 8;
    *(bf16x8*)(&Bt1[r * 136 + off]) = lst[v];
  }
  __syncthreads();                           // barrier 4

  // ---- phase 3b-lo: O += Q * State_lo (Bt1) ----
  #pragma unroll
  for (int hs = 0; hs < 4; hs++){
    bf16x8 bf[2];
    #pragma unroll
    for (int tn = 0; tn < 2; tn++)
      bf[tn] = *(const bf16x8*)(&Bt1[(wcol + tn * 16 + lr) * 136 + hs * 32 + lq * 8]);
    #pragma unroll
    for (int tm = 0; tm < 2; tm++)
      #pragma unroll
      for (int tn = 0; tn < 2; tn++)
        acc[tm][tn] = __builtin_amdgcn_mfma_f32_16x16x32_bf16(
            aq[tm][hs], bf[tn], acc[tm][tn], 0, 0, 0);
  }

  // ---- epilogue ----
  float* ob = out + ((size_t)b * S_ + i * 128 + roff) * H_;
  #pragma unroll
  for (int tm = 0; tm < 2; tm++)
    #pragma unroll
    for (int tn = 0; tn < 2; tn++)
      #pragma unroll
      for (int r4 = 0; r4 < 4; r4++){
        int row = tm * 16 + lq * 4 + r4;
        int col = wcol + tn * 16 + lr;
        ob[(size_t)row * H_ + col] = acc[tm][tn][r4];
      }
}

// ---------------------------------------------------------------------------
extern "C" void kernel_launch(void* const* d_in, const int* in_sizes, int n_in,
                              void* d_out, int out_size, void* d_ws, size_t ws_size,
                              hipStream_t stream) {
  // setup_inputs order: key, query, value, W_Q, W_K, W_V (all fp32)
  const float* key   = (const float*)d_in[0];
  const float* query = (const float*)d_in[1];
  const float* value = (const float*)d_in[2];
  const float* WQ    = (const float*)d_in[3];
  const float* WK    = (const float*)d_in[4];
  const float* WV    = (const float*)d_in[5];
  float* out = (float*)d_out;

  char* w = (char*)d_ws;
  short* WtQ = (short*)(w + 0);                       // 3 x 256 KB
  short* WtK = (short*)(w + 262144);
  short* WtV = (short*)(w + 524288);
  size_t o = 786432;
  short* q  = (short*)(w + o); o += 4194304;          // (B,S,H) bf16
  short* k  = (short*)(w + o); o += 4194304;
  short* kT = (short*)(w + o); o += 4194304;          // (B,H,S) bf16
  short* vT = (short*)(w + o); o += 4194304;
  short* Shi= (short*)(w + o); o += 4194304;          // exclusive prefix, bf16 hi
  short* Slo= (short*)(w + o); o += 4194304;          // bf16 residual

  wt_kernel   <<<dim3(32, 4, 3),       256, 0, stream>>>(WQ, WK, WV, WtQ, WtK, WtV);
  proj_kernel <<<dim3(256, 3),         256, 0, stream>>>(query, key, value,
                                                         WtQ, WtK, WtV, q, k, kT, vT);
  fused_state <<<dim3(4, 2, B_),       256, 0, stream>>>(vT, kT, Shi, Slo);
  passC       <<<dim3(NC_, 4, B_),     256, 0, stream>>>(q, k, vT, Shi, Slo, out);
}